// Round 7
// baseline (173.671 us; speedup 1.0000x reference)
//
#include <hip/hip_runtime.h>
#include <hip/hip_bf16.h>
#include <cmath>

#define D_MODEL 1024
#define N_HEADS 16
#define D_HEAD  64
#define BATCH   2
#define SEQ     2048
#define M_TOT   (BATCH*SEQ)   // 4096

typedef __attribute__((ext_vector_type(8))) short short8;   // 8 bf16 (4 VGPRs)
typedef __attribute__((ext_vector_type(4))) float f32x4;

// Q pre-scale: 1/sqrt(64) * log2(e)  (softmax computed base-2)
#define QSCALE (0.125f * 1.44269504088896f)

static __device__ __forceinline__ ushort f2bf(float f) {
    __hip_bfloat16 h = __float2bfloat16(f);   // RNE
    return *reinterpret_cast<ushort*>(&h);
}

static __device__ __forceinline__ void gload_lds16(const void* g, void* l) {
    __builtin_amdgcn_global_load_lds((const __attribute__((address_space(1))) unsigned*)g,
                                     (__attribute__((address_space(3))) unsigned*)l,
                                     16, 0, 0);
}

// ---------------------------------------------------------------------------
// fp32 -> bf16 elementwise (float4 in, ushort4 out)
// ---------------------------------------------------------------------------
__global__ __launch_bounds__(256)
void f32_to_bf16_kernel(const float* __restrict__ in, ushort* __restrict__ out, int n4)
{
    const int i = blockIdx.x * 256 + threadIdx.x;
    if (i < n4) {
        const float4 v = ((const float4*)in)[i];
        ushort4 u;
        u.x = f2bf(v.x); u.y = f2bf(v.y); u.z = f2bf(v.z); u.w = f2bf(v.w);
        ((ushort4*)out)[i] = u;
    }
}

// ---------------------------------------------------------------------------
// All four weights [1024][1024] fp32 -> Wt [N][K] bf16 (transpose + convert).
// ---------------------------------------------------------------------------
__global__ __launch_bounds__(256)
void transpose_w4_kernel(const float* __restrict__ W0, const float* __restrict__ W1,
                         const float* __restrict__ W2, const float* __restrict__ W3,
                         ushort* __restrict__ Wt0)
{
    __shared__ float Ts[64][65];
    const int z = blockIdx.z;
    const float* W = (z == 0) ? W0 : (z == 1) ? W1 : (z == 2) ? W2 : W3;
    ushort* Wt = Wt0 + (size_t)z * D_MODEL * D_MODEL;

    const int t  = threadIdx.x;
    const int n0 = blockIdx.x * 64;
    const int k0 = blockIdx.y * 64;
    const int rr = t >> 4;
    const int c4 = (t & 15) * 4;

#pragma unroll
    for (int i = 0; i < 4; ++i) {
        const int r = rr + i * 16;
        const float4 v = *(const float4*)&W[(size_t)(k0 + r) * D_MODEL + n0 + c4];
        Ts[r][c4 + 0] = v.x; Ts[r][c4 + 1] = v.y;
        Ts[r][c4 + 2] = v.z; Ts[r][c4 + 3] = v.w;
    }
    __syncthreads();
#pragma unroll
    for (int i = 0; i < 4; ++i) {
        const int nn = rr + i * 16;
        ushort4 u;
        u.x = f2bf(Ts[c4 + 0][nn]); u.y = f2bf(Ts[c4 + 1][nn]);
        u.z = f2bf(Ts[c4 + 2][nn]); u.w = f2bf(Ts[c4 + 3][nn]);
        *(ushort4*)&Wt[(size_t)(n0 + nn) * D_MODEL + k0 + c4] = u;
    }
}

// ---------------------------------------------------------------------------
// Merged QKV GEMM: bf16 MFMA, 128x128 tile, BK=64, 4 waves.
// proj 0/1 (Q/K): bf16 head layout [B][H][S][64]; Q pre-scaled by QSCALE.
// proj 2 (V):     bf16 TRANSPOSED head layout [B][H][64][S] (ushort4 stores).
// ---------------------------------------------------------------------------
__global__ __launch_bounds__(256)
void gemm_qkv_mfma(const ushort* __restrict__ A, const ushort* __restrict__ Bt,
                   const float* __restrict__ bq, const float* __restrict__ bk,
                   const float* __restrict__ bv, ushort* __restrict__ QKV)
{
    __shared__ ushort As[128 * 64];
    __shared__ ushort Bs[128 * 64];

    const int t    = threadIdx.x;
    const int lane = t & 63;
    const int w    = t >> 6;
    const int wr   = w >> 1;
    const int wc   = w & 1;
    const int l16  = lane & 15;
    const int g    = lane >> 4;
    const int m0   = blockIdx.y * 128;
    const int n0   = blockIdx.x * 128;

    f32x4 acc[4][4];
#pragma unroll
    for (int i = 0; i < 4; ++i)
#pragma unroll
        for (int j = 0; j < 4; ++j) acc[i][j] = f32x4{0.f, 0.f, 0.f, 0.f};

    for (int kt = 0; kt < D_MODEL; kt += 64) {
        __syncthreads();
        const ushort* Ag = A  + (size_t)m0 * D_MODEL + kt;
        const ushort* Bg = Bt + (size_t)n0 * D_MODEL + kt;
#pragma unroll
        for (int it = 0; it < 4; ++it) {
            const int b   = (it * 256 + t) * 16;
            const int row = b >> 7;
            const int src = (b & 127) ^ ((row & 7) << 4);
            const int lof = (it * 256 + (t & ~63)) * 8;
            gload_lds16(Ag + (size_t)row * D_MODEL + (src >> 1), As + lof);
            gload_lds16(Bg + (size_t)row * D_MODEL + (src >> 1), Bs + lof);
        }
        __syncthreads();

#pragma unroll
        for (int kh = 0; kh < 2; ++kh) {
            short8 a[4], bfr[4];
#pragma unroll
            for (int fm = 0; fm < 4; ++fm) {
                const int row  = wr * 64 + fm * 16 + l16;
                const int byte = row * 128 + (((kh << 6) | (g << 4)) ^ ((row & 7) << 4));
                a[fm] = *(const short8*)((const char*)As + byte);
            }
#pragma unroll
            for (int fn = 0; fn < 4; ++fn) {
                const int row  = wc * 64 + fn * 16 + l16;
                const int byte = row * 128 + (((kh << 6) | (g << 4)) ^ ((row & 7) << 4));
                bfr[fn] = *(const short8*)((const char*)Bs + byte);
            }
#pragma unroll
            for (int fm = 0; fm < 4; ++fm)
#pragma unroll
                for (int fn = 0; fn < 4; ++fn)
                    acc[fm][fn] = __builtin_amdgcn_mfma_f32_16x16x32_bf16(a[fm], bfr[fn], acc[fm][fn], 0, 0, 0);
        }
    }

#pragma unroll
    for (int fm = 0; fm < 4; ++fm) {
        const int mb  = m0 + wr * 64 + fm * 16 + g * 4;
        const int bb  = mb >> 11;
        const int sA  = mb & (SEQ - 1);
#pragma unroll
        for (int fn = 0; fn < 4; ++fn) {
            const int n    = n0 + wc * 64 + fn * 16 + l16;
            const int proj = n >> 10;
            const int nn   = n & 1023;
            const int h    = nn >> 6;
            const int dh   = nn & 63;
            const float bn = (proj == 0) ? bq[nn] : (proj == 1) ? bk[nn] : bv[nn];
            if (proj == 2) {
                // V transposed: 4 consecutive s -> one ushort4 store
                ushort4 pk;
                pk.x = f2bf(acc[fm][fn][0] + bn);
                pk.y = f2bf(acc[fm][fn][1] + bn);
                pk.z = f2bf(acc[fm][fn][2] + bn);
                pk.w = f2bf(acc[fm][fn][3] + bn);
                *(ushort4*)&QKV[2 * (size_t)M_TOT * D_MODEL +
                                (((size_t)(bb * N_HEADS + h)) * D_HEAD + dh) * SEQ + sA] = pk;
            } else {
                const float sc = (proj == 0) ? QSCALE : 1.0f;
                ushort* outp = QKV + (size_t)proj * M_TOT * D_MODEL;
#pragma unroll
                for (int r = 0; r < 4; ++r) {
                    const float c = (acc[fm][fn][r] + bn) * sc;
                    outp[(((size_t)(bb * N_HEADS + h)) * SEQ + sA + r) * D_HEAD + dh] = f2bf(c);
                }
            }
        }
    }
}

// ---------------------------------------------------------------------------
// Output-projection GEMM (bf16 MFMA, fp32 out): out = AO @ Wot^T + bo
// ---------------------------------------------------------------------------
__global__ __launch_bounds__(256)
void gemm_out_mfma(const ushort* __restrict__ A, const ushort* __restrict__ Bt,
                   const float* __restrict__ bias, float* __restrict__ outp)
{
    __shared__ ushort As[128 * 64];
    __shared__ ushort Bs[128 * 64];

    const int t    = threadIdx.x;
    const int lane = t & 63;
    const int w    = t >> 6;
    const int wr   = w >> 1;
    const int wc   = w & 1;
    const int l16  = lane & 15;
    const int g    = lane >> 4;
    const int m0   = blockIdx.y * 128;
    const int n0   = blockIdx.x * 128;

    f32x4 acc[4][4];
#pragma unroll
    for (int i = 0; i < 4; ++i)
#pragma unroll
        for (int j = 0; j < 4; ++j) acc[i][j] = f32x4{0.f, 0.f, 0.f, 0.f};

    for (int kt = 0; kt < D_MODEL; kt += 64) {
        __syncthreads();
        const ushort* Ag = A  + (size_t)m0 * D_MODEL + kt;
        const ushort* Bg = Bt + (size_t)n0 * D_MODEL + kt;
#pragma unroll
        for (int it = 0; it < 4; ++it) {
            const int b   = (it * 256 + t) * 16;
            const int row = b >> 7;
            const int src = (b & 127) ^ ((row & 7) << 4);
            const int lof = (it * 256 + (t & ~63)) * 8;
            gload_lds16(Ag + (size_t)row * D_MODEL + (src >> 1), As + lof);
            gload_lds16(Bg + (size_t)row * D_MODEL + (src >> 1), Bs + lof);
        }
        __syncthreads();

#pragma unroll
        for (int kh = 0; kh < 2; ++kh) {
            short8 a[4], bfr[4];
#pragma unroll
            for (int fm = 0; fm < 4; ++fm) {
                const int row  = wr * 64 + fm * 16 + l16;
                const int byte = row * 128 + (((kh << 6) | (g << 4)) ^ ((row & 7) << 4));
                a[fm] = *(const short8*)((const char*)As + byte);
            }
#pragma unroll
            for (int fn = 0; fn < 4; ++fn) {
                const int row  = wc * 64 + fn * 16 + l16;
                const int byte = row * 128 + (((kh << 6) | (g << 4)) ^ ((row & 7) << 4));
                bfr[fn] = *(const short8*)((const char*)Bs + byte);
            }
#pragma unroll
            for (int fm = 0; fm < 4; ++fm)
#pragma unroll
                for (int fn = 0; fn < 4; ++fn)
                    acc[fm][fn] = __builtin_amdgcn_mfma_f32_16x16x32_bf16(a[fm], bfr[fn], acc[fm][fn], 0, 0, 0);
        }
    }

#pragma unroll
    for (int fm = 0; fm < 4; ++fm) {
        const int mb = m0 + wr * 64 + fm * 16 + g * 4;
#pragma unroll
        for (int fn = 0; fn < 4; ++fn) {
            const int n  = n0 + wc * 64 + fn * 16 + l16;
            const float bn = bias[n];
#pragma unroll
            for (int r = 0; r < 4; ++r)
                outp[(size_t)(mb + r) * D_MODEL + n] = acc[fm][fn][r] + bn;
        }
    }
}

// ---------------------------------------------------------------------------
// Flash attention v4: swapped-QK^T, base-2 softmax, dbuf LDS K/V staging.
// Grid (SEQ/64, BH) = 1024 blocks (3 blocks/CU, LDS-capped). 4 waves; wave
// owns 16 q-rows. Stage(kt+1) issued before compute(kt); one barrier/iter.
// Defer-max (THR=8 in log2 units). Q pre-scaled by 1/8*log2(e) upstream.
// ---------------------------------------------------------------------------
__global__ __launch_bounds__(256)
void flash_attn_mfma(const ushort* __restrict__ Q, const ushort* __restrict__ K,
                     const ushort* __restrict__ Vt, ushort* __restrict__ AO)
{
    __shared__ ushort Kl[2][64 * 64];      // 64 keys x 64 d, swizzled rows
    __shared__ ushort Vl[2][64 * 64];      // 64 d x 64 keys, swizzled rows
    __shared__ ushort Ps[4][16][80];       // per-wave P tile (stride 80 = bank floor)

    const int t    = threadIdx.x;
    const int w    = t >> 6;
    const int lane = t & 63;
    const int l16  = lane & 15;
    const int g    = lane >> 4;
    const int qt   = blockIdx.x;
    const int bh   = blockIdx.y;

    const int q0 = qt * 64 + w * 16;
    const size_t qkbase = (size_t)bh * SEQ * D_HEAD;
    const ushort* Vg0 = Vt + (size_t)bh * D_HEAD * SEQ;

    short8 qf[2];
    {
        const ushort* qp = Q + qkbase + (size_t)(q0 + l16) * D_HEAD + g * 8;
        qf[0] = *(const short8*)(qp);
        qf[1] = *(const short8*)(qp + 32);
    }

    f32x4 o[4];
#pragma unroll
    for (int d = 0; d < 4; ++d) o[d] = f32x4{0.f, 0.f, 0.f, 0.f};
    float m_r = -INFINITY, l_r = 0.f;

    auto stage = [&](int ktile, int b) {
        const ushort* Kg = K + qkbase + (size_t)(ktile * 64) * D_HEAD;
        const ushort* Vg = Vg0 + ktile * 64;
#pragma unroll
        for (int it = 0; it < 2; ++it) {
            const int bb  = (it * 256 + t) * 16;
            const int row = bb >> 7;
            const int src = (bb & 127) ^ ((row & 7) << 4);
            const int lof = (it * 256 + (t & ~63)) * 8;
            gload_lds16(Kg + (size_t)row * D_HEAD + (src >> 1), &Kl[b][lof]);
            gload_lds16(Vg + (size_t)row * SEQ + (src >> 1), &Vl[b][lof]);
        }
    };

    stage(0, 0);
    __syncthreads();

    const int NT = SEQ / 64;
    for (int kt = 0; kt < NT; ++kt) {
        const int buf = kt & 1;
        if (kt + 1 < NT) stage(kt + 1, buf ^ 1);

        // ---- K fragments from LDS
        short8 kf[4][2];
#pragma unroll
        for (int nt = 0; nt < 4; ++nt) {
            const int row = nt * 16 + l16;
#pragma unroll
            for (int ks = 0; ks < 2; ++ks) {
                const int byte = row * 128 + (((ks * 64) | (g * 16)) ^ ((row & 7) << 4));
                kf[nt][ks] = *(const short8*)((const char*)&Kl[buf][0] + byte);
            }
        }

        // ---- S^T = K @ Q^T : st[nt][r] = S'[q=l16][key=nt*16+g*4+r] (log2 domain)
        f32x4 st[4];
        __builtin_amdgcn_s_setprio(1);
#pragma unroll
        for (int nt = 0; nt < 4; ++nt) {
            f32x4 a = f32x4{0.f, 0.f, 0.f, 0.f};
            a = __builtin_amdgcn_mfma_f32_16x16x32_bf16(kf[nt][0], qf[0], a, 0, 0, 0);
            a = __builtin_amdgcn_mfma_f32_16x16x32_bf16(kf[nt][1], qf[1], a, 0, 0, 0);
            st[nt] = a;
        }
        __builtin_amdgcn_s_setprio(0);

        // ---- base-2 online softmax, defer-max (row q = l16)
        float pmax = st[0][0];
#pragma unroll
        for (int nt = 0; nt < 4; ++nt)
#pragma unroll
            for (int r = 0; r < 4; ++r) pmax = fmaxf(pmax, st[nt][r]);
        pmax = fmaxf(pmax, __shfl_xor(pmax, 16, 64));
        pmax = fmaxf(pmax, __shfl_xor(pmax, 32, 64));

        if (__any(pmax - m_r > 8.f)) {
            const float mnew  = fmaxf(m_r, pmax);
            const float alpha = exp2f(m_r - mnew);
            m_r = mnew;
            l_r *= alpha;
            float ar[4];
#pragma unroll
            for (int r = 0; r < 4; ++r) ar[r] = __shfl(alpha, g * 4 + r, 64);
#pragma unroll
            for (int dt = 0; dt < 4; ++dt)
#pragma unroll
                for (int r = 0; r < 4; ++r) o[dt][r] *= ar[r];
        }

        float rs = 0.f;
#pragma unroll
        for (int nt = 0; nt < 4; ++nt) {
            ushort4 pk;
#pragma unroll
            for (int r = 0; r < 4; ++r) {
                const float p = exp2f(st[nt][r] - m_r);
                rs += p;
                ((ushort*)&pk)[r] = f2bf(p);
            }
            *(ushort4*)&Ps[w][l16][nt * 16 + g * 4] = pk;
        }
        rs += __shfl_xor(rs, 16, 64);
        rs += __shfl_xor(rs, 32, 64);
        l_r += rs;

        // ---- V fragments from LDS
        short8 vf[4][2];
#pragma unroll
        for (int dt = 0; dt < 4; ++dt) {
            const int row = dt * 16 + l16;
#pragma unroll
            for (int ks = 0; ks < 2; ++ks) {
                const int byte = row * 128 + (((ks * 64) | (g * 16)) ^ ((row & 7) << 4));
                vf[dt][ks] = *(const short8*)((const char*)&Vl[buf][0] + byte);
            }
        }

        // ---- O += P @ V
        __builtin_amdgcn_s_setprio(1);
#pragma unroll
        for (int ks = 0; ks < 2; ++ks) {
            const short8 pf = *(const short8*)&Ps[w][l16][ks * 32 + g * 8];
#pragma unroll
            for (int dt = 0; dt < 4; ++dt)
                o[dt] = __builtin_amdgcn_mfma_f32_16x16x32_bf16(pf, vf[dt][ks], o[dt], 0, 0, 0);
        }
        __builtin_amdgcn_s_setprio(0);

        __syncthreads();   // staging drained (vmcnt0); all reads of buf done
    }

    // ---- epilogue: AO[b][s][h*64+d] bf16
    float lr_row[4];
#pragma unroll
    for (int r = 0; r < 4; ++r) lr_row[r] = __shfl(l_r, g * 4 + r, 64);
    const int b = bh >> 4;
    const int h = bh & 15;
#pragma unroll
    for (int r = 0; r < 4; ++r) {
        const float inv = 1.f / lr_row[r];
        const size_t row = (size_t)b * SEQ + q0 + g * 4 + r;
#pragma unroll
        for (int dt = 0; dt < 4; ++dt)
            AO[row * D_MODEL + h * D_HEAD + dt * 16 + l16] = f2bf(o[dt][r] * inv);
    }
}

// ---------------------------------------------------------------------------
extern "C" void kernel_launch(void* const* d_in, const int* in_sizes, int n_in,
                              void* d_out, int out_size, void* d_ws, size_t ws_size,
                              hipStream_t stream)
{
    const float* x  = (const float*)d_in[0];
    const float* Wq = (const float*)d_in[1];
    const float* bq = (const float*)d_in[2];
    const float* Wk = (const float*)d_in[3];
    const float* bk = (const float*)d_in[4];
    const float* Wv = (const float*)d_in[5];
    const float* bv = (const float*)d_in[6];
    const float* Wo = (const float*)d_in[7];
    const float* bo = (const float*)d_in[8];
    float* out = (float*)d_out;

    const size_t NELT = (size_t)M_TOT * D_MODEL;     // 4M
    const size_t WELT = (size_t)D_MODEL * D_MODEL;   // 1M
    ushort* xb  = (ushort*)d_ws;        // [4096][1024] bf16
    ushort* Wqt = xb + NELT;            // Wq/Wk/Wv/Wo transposed, contiguous
    ushort* Wot = Wqt + 3 * WELT;
    ushort* Qb  = xb + 2 * NELT;        // Q head layout (pre-scaled, log2 domain)
    ushort* Kb  = Qb + NELT;            // K head layout
    ushort* Vtb = Kb + NELT;            // V TRANSPOSED head layout [bh][64][2048]
    ushort* AOb = xb + 5 * NELT;        // attention out, bf16 [4096][1024]

    f32_to_bf16_kernel<<<dim3(M_TOT * D_MODEL / 4 / 256), 256, 0, stream>>>(x, xb, M_TOT * D_MODEL / 4);
    transpose_w4_kernel<<<dim3(D_MODEL / 64, D_MODEL / 64, 4), 256, 0, stream>>>(Wq, Wk, Wv, Wo, Wqt);
    gemm_qkv_mfma<<<dim3(3 * D_MODEL / 128, M_TOT / 128), 256, 0, stream>>>(xb, Wqt, bq, bk, bv, Qb);
    flash_attn_mfma<<<dim3(SEQ / 64, BATCH * N_HEADS), 256, 0, stream>>>(Qb, Kb, Vtb, AOb);
    gemm_out_mfma<<<dim3(D_MODEL / 128, M_TOT / 128), 256, 0, stream>>>(AOb, Wot, bo, out);
}

// Round 8
// 166.719 us; speedup vs baseline: 1.0417x; 1.0417x over previous
//
#include <hip/hip_runtime.h>
#include <hip/hip_bf16.h>
#include <cmath>

#define D_MODEL 1024
#define N_HEADS 16
#define D_HEAD  64
#define BATCH   2
#define SEQ     2048
#define M_TOT   (BATCH*SEQ)   // 4096
#define NELT    ((size_t)M_TOT * D_MODEL)   // 4M elements

typedef __attribute__((ext_vector_type(8))) short short8;   // 8 bf16 (4 VGPRs)
typedef __attribute__((ext_vector_type(4))) float f32x4;

// Q pre-scale: 1/sqrt(64) * log2(e)  (softmax computed base-2)
#define QSCALE (0.125f * 1.44269504088896f)

static __device__ __forceinline__ ushort f2bf(float f) {
    __hip_bfloat16 h = __float2bfloat16(f);   // RNE
    return *reinterpret_cast<ushort*>(&h);
}
static __device__ __forceinline__ float bf2f(short u) {
    return __uint_as_float(((unsigned)(ushort)u) << 16);
}

static __device__ __forceinline__ void gload_lds16(const void* g, void* l) {
    __builtin_amdgcn_global_load_lds((const __attribute__((address_space(1))) unsigned*)g,
                                     (__attribute__((address_space(3))) unsigned*)l,
                                     16, 0, 0);
}

// ---------------------------------------------------------------------------
// fp32 -> bf16 elementwise (float4 in, ushort4 out)
// ---------------------------------------------------------------------------
__global__ __launch_bounds__(256)
void f32_to_bf16_kernel(const float* __restrict__ in, ushort* __restrict__ out, int n4)
{
    const int i = blockIdx.x * 256 + threadIdx.x;
    if (i < n4) {
        const float4 v = ((const float4*)in)[i];
        ushort4 u;
        u.x = f2bf(v.x); u.y = f2bf(v.y); u.z = f2bf(v.z); u.w = f2bf(v.w);
        ((ushort4*)out)[i] = u;
    }
}

// ---------------------------------------------------------------------------
// All four weights [1024][1024] fp32 -> Wt [N][K] bf16 (transpose + convert).
// ---------------------------------------------------------------------------
__global__ __launch_bounds__(256)
void transpose_w4_kernel(const float* __restrict__ W0, const float* __restrict__ W1,
                         const float* __restrict__ W2, const float* __restrict__ W3,
                         ushort* __restrict__ Wt0)
{
    __shared__ float Ts[64][65];
    const int z = blockIdx.z;
    const float* W = (z == 0) ? W0 : (z == 1) ? W1 : (z == 2) ? W2 : W3;
    ushort* Wt = Wt0 + (size_t)z * D_MODEL * D_MODEL;

    const int t  = threadIdx.x;
    const int n0 = blockIdx.x * 64;
    const int k0 = blockIdx.y * 64;
    const int rr = t >> 4;
    const int c4 = (t & 15) * 4;

#pragma unroll
    for (int i = 0; i < 4; ++i) {
        const int r = rr + i * 16;
        const float4 v = *(const float4*)&W[(size_t)(k0 + r) * D_MODEL + n0 + c4];
        Ts[r][c4 + 0] = v.x; Ts[r][c4 + 1] = v.y;
        Ts[r][c4 + 2] = v.z; Ts[r][c4 + 3] = v.w;
    }
    __syncthreads();
#pragma unroll
    for (int i = 0; i < 4; ++i) {
        const int nn = rr + i * 16;
        ushort4 u;
        u.x = f2bf(Ts[c4 + 0][nn]); u.y = f2bf(Ts[c4 + 1][nn]);
        u.z = f2bf(Ts[c4 + 2][nn]); u.w = f2bf(Ts[c4 + 3][nn]);
        *(ushort4*)&Wt[(size_t)(n0 + nn) * D_MODEL + k0 + c4] = u;
    }
}

// ---------------------------------------------------------------------------
// Merged QKV GEMM: bf16 MFMA, 128x128 tile, BK=64, 4 waves.
// proj 0/1 (Q/K): bf16 head layout [B][H][S][64]; Q pre-scaled by QSCALE.
// proj 2 (V):     bf16 TRANSPOSED head layout [B][H][64][S] (ushort4 stores).
// ---------------------------------------------------------------------------
__global__ __launch_bounds__(256)
void gemm_qkv_mfma(const ushort* __restrict__ A, const ushort* __restrict__ Bt,
                   const float* __restrict__ bq, const float* __restrict__ bk,
                   const float* __restrict__ bv, ushort* __restrict__ QKV)
{
    __shared__ ushort As[128 * 64];
    __shared__ ushort Bs[128 * 64];

    const int t    = threadIdx.x;
    const int lane = t & 63;
    const int w    = t >> 6;
    const int wr   = w >> 1;
    const int wc   = w & 1;
    const int l16  = lane & 15;
    const int g    = lane >> 4;
    const int m0   = blockIdx.y * 128;
    const int n0   = blockIdx.x * 128;

    f32x4 acc[4][4];
#pragma unroll
    for (int i = 0; i < 4; ++i)
#pragma unroll
        for (int j = 0; j < 4; ++j) acc[i][j] = f32x4{0.f, 0.f, 0.f, 0.f};

    for (int kt = 0; kt < D_MODEL; kt += 64) {
        __syncthreads();
        const ushort* Ag = A  + (size_t)m0 * D_MODEL + kt;
        const ushort* Bg = Bt + (size_t)n0 * D_MODEL + kt;
#pragma unroll
        for (int it = 0; it < 4; ++it) {
            const int b   = (it * 256 + t) * 16;
            const int row = b >> 7;
            const int src = (b & 127) ^ ((row & 7) << 4);
            const int lof = (it * 256 + (t & ~63)) * 8;
            gload_lds16(Ag + (size_t)row * D_MODEL + (src >> 1), As + lof);
            gload_lds16(Bg + (size_t)row * D_MODEL + (src >> 1), Bs + lof);
        }
        __syncthreads();

#pragma unroll
        for (int kh = 0; kh < 2; ++kh) {
            short8 a[4], bfr[4];
#pragma unroll
            for (int fm = 0; fm < 4; ++fm) {
                const int row  = wr * 64 + fm * 16 + l16;
                const int byte = row * 128 + (((kh << 6) | (g << 4)) ^ ((row & 7) << 4));
                a[fm] = *(const short8*)((const char*)As + byte);
            }
#pragma unroll
            for (int fn = 0; fn < 4; ++fn) {
                const int row  = wc * 64 + fn * 16 + l16;
                const int byte = row * 128 + (((kh << 6) | (g << 4)) ^ ((row & 7) << 4));
                bfr[fn] = *(const short8*)((const char*)Bs + byte);
            }
#pragma unroll
            for (int fm = 0; fm < 4; ++fm)
#pragma unroll
                for (int fn = 0; fn < 4; ++fn)
                    acc[fm][fn] = __builtin_amdgcn_mfma_f32_16x16x32_bf16(a[fm], bfr[fn], acc[fm][fn], 0, 0, 0);
        }
    }

#pragma unroll
    for (int fm = 0; fm < 4; ++fm) {
        const int mb  = m0 + wr * 64 + fm * 16 + g * 4;
        const int bb  = mb >> 11;
        const int sA  = mb & (SEQ - 1);
#pragma unroll
        for (int fn = 0; fn < 4; ++fn) {
            const int n    = n0 + wc * 64 + fn * 16 + l16;
            const int proj = n >> 10;
            const int nn   = n & 1023;
            const int h    = nn >> 6;
            const int dh   = nn & 63;
            const float bn = (proj == 0) ? bq[nn] : (proj == 1) ? bk[nn] : bv[nn];
            if (proj == 2) {
                // V transposed: 4 consecutive s -> one ushort4 store
                ushort4 pk;
                pk.x = f2bf(acc[fm][fn][0] + bn);
                pk.y = f2bf(acc[fm][fn][1] + bn);
                pk.z = f2bf(acc[fm][fn][2] + bn);
                pk.w = f2bf(acc[fm][fn][3] + bn);
                *(ushort4*)&QKV[2 * NELT +
                                (((size_t)(bb * N_HEADS + h)) * D_HEAD + dh) * SEQ + sA] = pk;
            } else {
                const float sc = (proj == 0) ? QSCALE : 1.0f;
                ushort* outp = QKV + (size_t)proj * NELT;
#pragma unroll
                for (int r = 0; r < 4; ++r) {
                    const float c = (acc[fm][fn][r] + bn) * sc;
                    outp[(((size_t)(bb * N_HEADS + h)) * SEQ + sA + r) * D_HEAD + dh] = f2bf(c);
                }
            }
        }
    }
}

// ---------------------------------------------------------------------------
// Output-projection GEMM (bf16 MFMA, fp32 out): out = AO @ Wot^T + bo
// ---------------------------------------------------------------------------
__global__ __launch_bounds__(256)
void gemm_out_mfma(const ushort* __restrict__ A, const ushort* __restrict__ Bt,
                   const float* __restrict__ bias, float* __restrict__ outp)
{
    __shared__ ushort As[128 * 64];
    __shared__ ushort Bs[128 * 64];

    const int t    = threadIdx.x;
    const int lane = t & 63;
    const int w    = t >> 6;
    const int wr   = w >> 1;
    const int wc   = w & 1;
    const int l16  = lane & 15;
    const int g    = lane >> 4;
    const int m0   = blockIdx.y * 128;
    const int n0   = blockIdx.x * 128;

    f32x4 acc[4][4];
#pragma unroll
    for (int i = 0; i < 4; ++i)
#pragma unroll
        for (int j = 0; j < 4; ++j) acc[i][j] = f32x4{0.f, 0.f, 0.f, 0.f};

    for (int kt = 0; kt < D_MODEL; kt += 64) {
        __syncthreads();
        const ushort* Ag = A  + (size_t)m0 * D_MODEL + kt;
        const ushort* Bg = Bt + (size_t)n0 * D_MODEL + kt;
#pragma unroll
        for (int it = 0; it < 4; ++it) {
            const int b   = (it * 256 + t) * 16;
            const int row = b >> 7;
            const int src = (b & 127) ^ ((row & 7) << 4);
            const int lof = (it * 256 + (t & ~63)) * 8;
            gload_lds16(Ag + (size_t)row * D_MODEL + (src >> 1), As + lof);
            gload_lds16(Bg + (size_t)row * D_MODEL + (src >> 1), Bs + lof);
        }
        __syncthreads();

#pragma unroll
        for (int kh = 0; kh < 2; ++kh) {
            short8 a[4], bfr[4];
#pragma unroll
            for (int fm = 0; fm < 4; ++fm) {
                const int row  = wr * 64 + fm * 16 + l16;
                const int byte = row * 128 + (((kh << 6) | (g << 4)) ^ ((row & 7) << 4));
                a[fm] = *(const short8*)((const char*)As + byte);
            }
#pragma unroll
            for (int fn = 0; fn < 4; ++fn) {
                const int row  = wc * 64 + fn * 16 + l16;
                const int byte = row * 128 + (((kh << 6) | (g << 4)) ^ ((row & 7) << 4));
                bfr[fn] = *(const short8*)((const char*)Bs + byte);
            }
#pragma unroll
            for (int fm = 0; fm < 4; ++fm)
#pragma unroll
                for (int fn = 0; fn < 4; ++fn)
                    acc[fm][fn] = __builtin_amdgcn_mfma_f32_16x16x32_bf16(a[fm], bfr[fn], acc[fm][fn], 0, 0, 0);
        }
    }

#pragma unroll
    for (int fm = 0; fm < 4; ++fm) {
        const int mb = m0 + wr * 64 + fm * 16 + g * 4;
#pragma unroll
        for (int fn = 0; fn < 4; ++fn) {
            const int n  = n0 + wc * 64 + fn * 16 + l16;
            const float bn = bias[n];
#pragma unroll
            for (int r = 0; r < 4; ++r)
                outp[(size_t)(mb + r) * D_MODEL + n] = acc[fm][fn][r] + bn;
        }
    }
}

// ---------------------------------------------------------------------------
// Flash attention v5: v3 tile shape (wave = 32 q-rows, 2 subtiles) + KV-split.
// Grid (2*SEQ/128, BH) = 1024 blocks; hv = blockIdx.x&1 selects key half
// [hv*1024, hv*1024+1024). Swapped-QK^T, base-2 softmax, defer-max, dbuf LDS
// K/V staging (XOR-swizzled src + linear gload_lds dest + swizzled ds_read).
// Writes normalized partial O (bf16, [hv][bh][s][64]) + (m,l) fp32 per row.
// ---------------------------------------------------------------------------
__global__ __launch_bounds__(256)
void flash_attn_split(const ushort* __restrict__ Q, const ushort* __restrict__ K,
                      const ushort* __restrict__ Vt, ushort* __restrict__ Opart,
                      float2* __restrict__ ML)
{
    __shared__ ushort Kl[2][64 * 64];      // 64 keys x 64 d, swizzled rows
    __shared__ ushort Vl[2][64 * 64];      // 64 d x 64 keys, swizzled rows
    __shared__ ushort Ps[4][2][16][80];    // [wave][subtile][q][key]

    const int t    = threadIdx.x;
    const int w    = t >> 6;
    const int lane = t & 63;
    const int l16  = lane & 15;
    const int g    = lane >> 4;
    const int hv   = blockIdx.x & 1;
    const int qt   = blockIdx.x >> 1;
    const int bh   = blockIdx.y;

    const size_t qkbase = (size_t)bh * SEQ * D_HEAD;
    const ushort* Vg0 = Vt + (size_t)bh * D_HEAD * SEQ;

    short8 qf[2][2];
#pragma unroll
    for (int tt = 0; tt < 2; ++tt) {
        const int q0 = qt * 128 + w * 32 + tt * 16;
        const ushort* qp = Q + qkbase + (size_t)(q0 + l16) * D_HEAD + g * 8;
        qf[tt][0] = *(const short8*)(qp);
        qf[tt][1] = *(const short8*)(qp + 32);
    }

    f32x4 o[2][4];
    float m_r[2], l_r[2];
#pragma unroll
    for (int tt = 0; tt < 2; ++tt) {
        m_r[tt] = -INFINITY; l_r[tt] = 0.f;
#pragma unroll
        for (int d = 0; d < 4; ++d) o[tt][d] = f32x4{0.f, 0.f, 0.f, 0.f};
    }

    auto stage = [&](int ktile, int b) {
        const ushort* Kg = K + qkbase + (size_t)(ktile * 64) * D_HEAD;
        const ushort* Vg = Vg0 + ktile * 64;
#pragma unroll
        for (int it = 0; it < 2; ++it) {
            const int bb  = (it * 256 + t) * 16;
            const int row = bb >> 7;
            const int src = (bb & 127) ^ ((row & 7) << 4);
            const int lof = (it * 256 + (t & ~63)) * 8;
            gload_lds16(Kg + (size_t)row * D_HEAD + (src >> 1), &Kl[b][lof]);
            gload_lds16(Vg + (size_t)row * SEQ + (src >> 1), &Vl[b][lof]);
        }
    };

    const int it0 = hv * 16;   // 16 key-tiles per half
    stage(it0, 0);
    __syncthreads();

    for (int it = 0; it < 16; ++it) {
        const int buf = it & 1;
        if (it + 1 < 16) stage(it0 + it + 1, buf ^ 1);

        // ---- K fragments from LDS (shared by both sub-tiles)
        short8 kf[4][2];
#pragma unroll
        for (int nt = 0; nt < 4; ++nt) {
            const int row = nt * 16 + l16;
#pragma unroll
            for (int ks = 0; ks < 2; ++ks) {
                const int byte = row * 128 + (((ks * 64) | (g * 16)) ^ ((row & 7) << 4));
                kf[nt][ks] = *(const short8*)((const char*)&Kl[buf][0] + byte);
            }
        }

        // ---- S^T = K @ Q^T for both sub-tiles (log2 domain)
        f32x4 st[2][4];
        __builtin_amdgcn_s_setprio(1);
#pragma unroll
        for (int tt = 0; tt < 2; ++tt)
#pragma unroll
            for (int nt = 0; nt < 4; ++nt) {
                f32x4 a = f32x4{0.f, 0.f, 0.f, 0.f};
                a = __builtin_amdgcn_mfma_f32_16x16x32_bf16(kf[nt][0], qf[tt][0], a, 0, 0, 0);
                a = __builtin_amdgcn_mfma_f32_16x16x32_bf16(kf[nt][1], qf[tt][1], a, 0, 0, 0);
                st[tt][nt] = a;
            }
        __builtin_amdgcn_s_setprio(0);

        // ---- base-2 online softmax per sub-tile (row q = l16; defer-max THR=8)
#pragma unroll
        for (int tt = 0; tt < 2; ++tt) {
            float pmax = st[tt][0][0];
#pragma unroll
            for (int nt = 0; nt < 4; ++nt)
#pragma unroll
                for (int r = 0; r < 4; ++r) pmax = fmaxf(pmax, st[tt][nt][r]);
            pmax = fmaxf(pmax, __shfl_xor(pmax, 16, 64));
            pmax = fmaxf(pmax, __shfl_xor(pmax, 32, 64));

            if (__any(pmax - m_r[tt] > 8.f)) {
                const float mnew  = fmaxf(m_r[tt], pmax);
                const float alpha = exp2f(m_r[tt] - mnew);
                m_r[tt] = mnew;
                l_r[tt] *= alpha;
                float ar[4];
#pragma unroll
                for (int r = 0; r < 4; ++r) ar[r] = __shfl(alpha, g * 4 + r, 64);
#pragma unroll
                for (int dt = 0; dt < 4; ++dt)
#pragma unroll
                    for (int r = 0; r < 4; ++r) o[tt][dt][r] *= ar[r];
            }

            float rs = 0.f;
#pragma unroll
            for (int nt = 0; nt < 4; ++nt) {
                ushort4 pk;
#pragma unroll
                for (int r = 0; r < 4; ++r) {
                    const float p = exp2f(st[tt][nt][r] - m_r[tt]);
                    rs += p;
                    ((ushort*)&pk)[r] = f2bf(p);
                }
                *(ushort4*)&Ps[w][tt][l16][nt * 16 + g * 4] = pk;
            }
            rs += __shfl_xor(rs, 16, 64);
            rs += __shfl_xor(rs, 32, 64);
            l_r[tt] += rs;
        }

        // ---- V fragments from LDS (shared by both sub-tiles)
        short8 vf[4][2];
#pragma unroll
        for (int dt = 0; dt < 4; ++dt) {
            const int row = dt * 16 + l16;
#pragma unroll
            for (int ks = 0; ks < 2; ++ks) {
                const int byte = row * 128 + (((ks * 64) | (g * 16)) ^ ((row & 7) << 4));
                vf[dt][ks] = *(const short8*)((const char*)&Vl[buf][0] + byte);
            }
        }

        // ---- O += P @ V for both sub-tiles
        __builtin_amdgcn_s_setprio(1);
#pragma unroll
        for (int tt = 0; tt < 2; ++tt)
#pragma unroll
            for (int ks = 0; ks < 2; ++ks) {
                const short8 pf = *(const short8*)&Ps[w][tt][l16][ks * 32 + g * 8];
#pragma unroll
                for (int dt = 0; dt < 4; ++dt)
                    o[tt][dt] = __builtin_amdgcn_mfma_f32_16x16x32_bf16(pf, vf[dt][ks], o[tt][dt], 0, 0, 0);
            }
        __builtin_amdgcn_s_setprio(0);

        __syncthreads();   // staging drained (vmcnt0); all reads of buf done
    }

    // ---- epilogue: normalized partial O -> Opart[hv][bh][s][64]; (m,l) -> ML
#pragma unroll
    for (int tt = 0; tt < 2; ++tt) {
        const int q0 = qt * 128 + w * 32 + tt * 16;
        float lr_row[4];
#pragma unroll
        for (int r = 0; r < 4; ++r) lr_row[r] = __shfl(l_r[tt], g * 4 + r, 64);
#pragma unroll
        for (int r = 0; r < 4; ++r) {
            const float inv = 1.f / lr_row[r];
            const size_t row = (size_t)bh * SEQ + q0 + g * 4 + r;
#pragma unroll
            for (int dt = 0; dt < 4; ++dt)
                Opart[(size_t)hv * NELT + row * D_HEAD + dt * 16 + l16] =
                    f2bf(o[tt][dt][r] * inv);
        }
        if (g == 0)
            ML[(size_t)hv * BATCH * N_HEADS * SEQ + (size_t)bh * SEQ + q0 + l16] =
                make_float2(m_r[tt], l_r[tt]);
    }
}

// ---------------------------------------------------------------------------
// Merge the two KV-halves: AO = w1*O1 + w2*O2, w_i = l_i*2^(m_i-m) / sum.
// Output AO in [B][S][H*64] bf16 (feeds o-projection GEMM).
// ---------------------------------------------------------------------------
__global__ __launch_bounds__(256)
void merge_attn(const ushort* __restrict__ Opart, const float2* __restrict__ ML,
                ushort* __restrict__ AO)
{
    const int idx = blockIdx.x * 256 + threadIdx.x;   // 32*2048*8 total
    const int dh8 = idx & 7;
    const int s   = (idx >> 3) & (SEQ - 1);
    const int bh  = idx >> 14;
    const size_t rowh = (size_t)bh * SEQ + s;

    const float2 ml1 = ML[rowh];
    const float2 ml2 = ML[(size_t)BATCH * N_HEADS * SEQ + rowh];
    const float m   = fmaxf(ml1.x, ml2.x);
    const float c1  = ml1.y * exp2f(ml1.x - m);
    const float c2  = ml2.y * exp2f(ml2.x - m);
    const float inv = 1.f / (c1 + c2);
    const float w1  = c1 * inv;
    const float w2  = c2 * inv;

    const size_t off = rowh * D_HEAD + dh8 * 8;
    const short8 o1 = *(const short8*)&Opart[off];
    const short8 o2 = *(const short8*)&Opart[NELT + off];
    short8 res;
#pragma unroll
    for (int j = 0; j < 8; ++j)
        res[j] = (short)f2bf(w1 * bf2f(o1[j]) + w2 * bf2f(o2[j]));

    const int b = bh >> 4;
    const int h = bh & 15;
    *(short8*)&AO[((size_t)b * SEQ + s) * D_MODEL + h * D_HEAD + dh8 * 8] = res;
}

// ---------------------------------------------------------------------------
extern "C" void kernel_launch(void* const* d_in, const int* in_sizes, int n_in,
                              void* d_out, int out_size, void* d_ws, size_t ws_size,
                              hipStream_t stream)
{
    const float* x  = (const float*)d_in[0];
    const float* Wq = (const float*)d_in[1];
    const float* bq = (const float*)d_in[2];
    const float* Wk = (const float*)d_in[3];
    const float* bk = (const float*)d_in[4];
    const float* Wv = (const float*)d_in[5];
    const float* bv = (const float*)d_in[6];
    const float* Wo = (const float*)d_in[7];
    const float* bo = (const float*)d_in[8];
    float* out = (float*)d_out;

    const size_t WELT = (size_t)D_MODEL * D_MODEL;   // 1M
    ushort* xb    = (ushort*)d_ws;       // [0,1N): x bf16; later AO (merge out)
    ushort* Wqt   = xb + NELT;           // [1N,2N): Wq/Wk/Wv/Wo transposed
    ushort* Wot   = Wqt + 3 * WELT;
    ushort* Qb    = xb + 2 * NELT;       // [2N,3N): Q head layout (pre-scaled)
    ushort* Kb    = Qb + NELT;           // [3N,4N)
    ushort* Vtb   = Kb + NELT;           // [4N,5N): V transposed head layout
    ushort* Opart = xb + 5 * NELT;       // [5N,7N): two bf16 partial-O halves
    float2* ML    = (float2*)(xb + 7 * NELT);   // 1 MB: (m,l) per half/row
    ushort* AOb   = xb;                  // merge output aliases xb (x dead)

    f32_to_bf16_kernel<<<dim3(M_TOT * D_MODEL / 4 / 256), 256, 0, stream>>>(x, xb, M_TOT * D_MODEL / 4);
    transpose_w4_kernel<<<dim3(D_MODEL / 64, D_MODEL / 64, 4), 256, 0, stream>>>(Wq, Wk, Wv, Wo, Wqt);
    gemm_qkv_mfma<<<dim3(3 * D_MODEL / 128, M_TOT / 128), 256, 0, stream>>>(xb, Wqt, bq, bk, bv, Qb);
    flash_attn_split<<<dim3(2 * SEQ / 128, BATCH * N_HEADS), 256, 0, stream>>>(Qb, Kb, Vtb, Opart, ML);
    merge_attn<<<dim3(BATCH * N_HEADS * SEQ * 8 / 256), 256, 0, stream>>>(Opart, ML, AOb);
    gemm_out_mfma<<<dim3(D_MODEL / 128, M_TOT / 128), 256, 0, stream>>>(AOb, Wot, bo, out);
}

// Round 9
// 153.062 us; speedup vs baseline: 1.1346x; 1.0892x over previous
//
#include <hip/hip_runtime.h>
#include <hip/hip_bf16.h>
#include <cmath>

#define D_MODEL 1024
#define N_HEADS 16
#define D_HEAD  64
#define BATCH   2
#define SEQ     2048
#define M_TOT   (BATCH*SEQ)   // 4096
#define NELT    ((size_t)M_TOT * D_MODEL)   // 4M elements

typedef __attribute__((ext_vector_type(8)))  short short8;   // 8 bf16 (4 VGPRs)
typedef __attribute__((ext_vector_type(4)))  float f32x4;
typedef __attribute__((ext_vector_type(16))) float f32x16;
typedef __attribute__((ext_vector_type(4)))  unsigned uint4v;

// Q pre-scale: 1/sqrt(64) * log2(e)  (softmax computed base-2)
#define QSCALE (0.125f * 1.44269504088896f)

static __device__ __forceinline__ ushort f2bf(float f) {
    __hip_bfloat16 h = __float2bfloat16(f);   // RNE
    return *reinterpret_cast<ushort*>(&h);
}

static __device__ __forceinline__ unsigned cvtpk_bf16(float lo, float hi) {
    unsigned r;
    asm("v_cvt_pk_bf16_f32 %0, %1, %2" : "=v"(r) : "v"(lo), "v"(hi));
    return r;
}

static __device__ __forceinline__ void gload_lds16(const void* g, void* l) {
    __builtin_amdgcn_global_load_lds((const __attribute__((address_space(1))) unsigned*)g,
                                     (__attribute__((address_space(3))) unsigned*)l,
                                     16, 0, 0);
}

// ---------------------------------------------------------------------------
// fp32 -> bf16 elementwise (float4 in, ushort4 out)
// ---------------------------------------------------------------------------
__global__ __launch_bounds__(256)
void f32_to_bf16_kernel(const float* __restrict__ in, ushort* __restrict__ out, int n4)
{
    const int i = blockIdx.x * 256 + threadIdx.x;
    if (i < n4) {
        const float4 v = ((const float4*)in)[i];
        ushort4 u;
        u.x = f2bf(v.x); u.y = f2bf(v.y); u.z = f2bf(v.z); u.w = f2bf(v.w);
        ((ushort4*)out)[i] = u;
    }
}

// ---------------------------------------------------------------------------
// All four weights [1024][1024] fp32 -> Wt [N][K] bf16 (transpose + convert).
// ---------------------------------------------------------------------------
__global__ __launch_bounds__(256)
void transpose_w4_kernel(const float* __restrict__ W0, const float* __restrict__ W1,
                         const float* __restrict__ W2, const float* __restrict__ W3,
                         ushort* __restrict__ Wt0)
{
    __shared__ float Ts[64][65];
    const int z = blockIdx.z;
    const float* W = (z == 0) ? W0 : (z == 1) ? W1 : (z == 2) ? W2 : W3;
    ushort* Wt = Wt0 + (size_t)z * D_MODEL * D_MODEL;

    const int t  = threadIdx.x;
    const int n0 = blockIdx.x * 64;
    const int k0 = blockIdx.y * 64;
    const int rr = t >> 4;
    const int c4 = (t & 15) * 4;

#pragma unroll
    for (int i = 0; i < 4; ++i) {
        const int r = rr + i * 16;
        const float4 v = *(const float4*)&W[(size_t)(k0 + r) * D_MODEL + n0 + c4];
        Ts[r][c4 + 0] = v.x; Ts[r][c4 + 1] = v.y;
        Ts[r][c4 + 2] = v.z; Ts[r][c4 + 3] = v.w;
    }
    __syncthreads();
#pragma unroll
    for (int i = 0; i < 4; ++i) {
        const int nn = rr + i * 16;
        ushort4 u;
        u.x = f2bf(Ts[c4 + 0][nn]); u.y = f2bf(Ts[c4 + 1][nn]);
        u.z = f2bf(Ts[c4 + 2][nn]); u.w = f2bf(Ts[c4 + 3][nn]);
        *(ushort4*)&Wt[(size_t)(n0 + nn) * D_MODEL + k0 + c4] = u;
    }
}

// ---------------------------------------------------------------------------
// Merged QKV GEMM: bf16 MFMA, 128x128 tile, BK=64, 4 waves.
// proj 0/1 (Q/K): bf16 head layout [B][H][S][64]; Q pre-scaled by QSCALE.
// proj 2 (V):     bf16 TRANSPOSED head layout [B][H][64][S] (ushort4 stores).
// ---------------------------------------------------------------------------
__global__ __launch_bounds__(256)
void gemm_qkv_mfma(const ushort* __restrict__ A, const ushort* __restrict__ Bt,
                   const float* __restrict__ bq, const float* __restrict__ bk,
                   const float* __restrict__ bv, ushort* __restrict__ QKV)
{
    __shared__ ushort As[128 * 64];
    __shared__ ushort Bs[128 * 64];

    const int t    = threadIdx.x;
    const int lane = t & 63;
    const int w    = t >> 6;
    const int wr   = w >> 1;
    const int wc   = w & 1;
    const int l16  = lane & 15;
    const int g    = lane >> 4;
    const int m0   = blockIdx.y * 128;
    const int n0   = blockIdx.x * 128;

    f32x4 acc[4][4];
#pragma unroll
    for (int i = 0; i < 4; ++i)
#pragma unroll
        for (int j = 0; j < 4; ++j) acc[i][j] = f32x4{0.f, 0.f, 0.f, 0.f};

    for (int kt = 0; kt < D_MODEL; kt += 64) {
        __syncthreads();
        const ushort* Ag = A  + (size_t)m0 * D_MODEL + kt;
        const ushort* Bg = Bt + (size_t)n0 * D_MODEL + kt;
#pragma unroll
        for (int it = 0; it < 4; ++it) {
            const int b   = (it * 256 + t) * 16;
            const int row = b >> 7;
            const int src = (b & 127) ^ ((row & 7) << 4);
            const int lof = (it * 256 + (t & ~63)) * 8;
            gload_lds16(Ag + (size_t)row * D_MODEL + (src >> 1), As + lof);
            gload_lds16(Bg + (size_t)row * D_MODEL + (src >> 1), Bs + lof);
        }
        __syncthreads();

#pragma unroll
        for (int kh = 0; kh < 2; ++kh) {
            short8 a[4], bfr[4];
#pragma unroll
            for (int fm = 0; fm < 4; ++fm) {
                const int row  = wr * 64 + fm * 16 + l16;
                const int byte = row * 128 + (((kh << 6) | (g << 4)) ^ ((row & 7) << 4));
                a[fm] = *(const short8*)((const char*)As + byte);
            }
#pragma unroll
            for (int fn = 0; fn < 4; ++fn) {
                const int row  = wc * 64 + fn * 16 + l16;
                const int byte = row * 128 + (((kh << 6) | (g << 4)) ^ ((row & 7) << 4));
                bfr[fn] = *(const short8*)((const char*)Bs + byte);
            }
#pragma unroll
            for (int fm = 0; fm < 4; ++fm)
#pragma unroll
                for (int fn = 0; fn < 4; ++fn)
                    acc[fm][fn] = __builtin_amdgcn_mfma_f32_16x16x32_bf16(a[fm], bfr[fn], acc[fm][fn], 0, 0, 0);
        }
    }

#pragma unroll
    for (int fm = 0; fm < 4; ++fm) {
        const int mb  = m0 + wr * 64 + fm * 16 + g * 4;
        const int bb  = mb >> 11;
        const int sA  = mb & (SEQ - 1);
#pragma unroll
        for (int fn = 0; fn < 4; ++fn) {
            const int n    = n0 + wc * 64 + fn * 16 + l16;
            const int proj = n >> 10;
            const int nn   = n & 1023;
            const int h    = nn >> 6;
            const int dh   = nn & 63;
            const float bn = (proj == 0) ? bq[nn] : (proj == 1) ? bk[nn] : bv[nn];
            if (proj == 2) {
                ushort4 pk;
                pk.x = f2bf(acc[fm][fn][0] + bn);
                pk.y = f2bf(acc[fm][fn][1] + bn);
                pk.z = f2bf(acc[fm][fn][2] + bn);
                pk.w = f2bf(acc[fm][fn][3] + bn);
                *(ushort4*)&QKV[2 * NELT +
                                (((size_t)(bb * N_HEADS + h)) * D_HEAD + dh) * SEQ + sA] = pk;
            } else {
                const float sc = (proj == 0) ? QSCALE : 1.0f;
                ushort* outp = QKV + (size_t)proj * NELT;
#pragma unroll
                for (int r = 0; r < 4; ++r) {
                    const float c = (acc[fm][fn][r] + bn) * sc;
                    outp[(((size_t)(bb * N_HEADS + h)) * SEQ + sA + r) * D_HEAD + dh] = f2bf(c);
                }
            }
        }
    }
}

// ---------------------------------------------------------------------------
// Output-projection GEMM (bf16 MFMA, fp32 out): out = AO @ Wot^T + bo
// ---------------------------------------------------------------------------
__global__ __launch_bounds__(256)
void gemm_out_mfma(const ushort* __restrict__ A, const ushort* __restrict__ Bt,
                   const float* __restrict__ bias, float* __restrict__ outp)
{
    __shared__ ushort As[128 * 64];
    __shared__ ushort Bs[128 * 64];

    const int t    = threadIdx.x;
    const int lane = t & 63;
    const int w    = t >> 6;
    const int wr   = w >> 1;
    const int wc   = w & 1;
    const int l16  = lane & 15;
    const int g    = lane >> 4;
    const int m0   = blockIdx.y * 128;
    const int n0   = blockIdx.x * 128;

    f32x4 acc[4][4];
#pragma unroll
    for (int i = 0; i < 4; ++i)
#pragma unroll
        for (int j = 0; j < 4; ++j) acc[i][j] = f32x4{0.f, 0.f, 0.f, 0.f};

    for (int kt = 0; kt < D_MODEL; kt += 64) {
        __syncthreads();
        const ushort* Ag = A  + (size_t)m0 * D_MODEL + kt;
        const ushort* Bg = Bt + (size_t)n0 * D_MODEL + kt;
#pragma unroll
        for (int it = 0; it < 4; ++it) {
            const int b   = (it * 256 + t) * 16;
            const int row = b >> 7;
            const int src = (b & 127) ^ ((row & 7) << 4);
            const int lof = (it * 256 + (t & ~63)) * 8;
            gload_lds16(Ag + (size_t)row * D_MODEL + (src >> 1), As + lof);
            gload_lds16(Bg + (size_t)row * D_MODEL + (src >> 1), Bs + lof);
        }
        __syncthreads();

#pragma unroll
        for (int kh = 0; kh < 2; ++kh) {
            short8 a[4], bfr[4];
#pragma unroll
            for (int fm = 0; fm < 4; ++fm) {
                const int row  = wr * 64 + fm * 16 + l16;
                const int byte = row * 128 + (((kh << 6) | (g << 4)) ^ ((row & 7) << 4));
                a[fm] = *(const short8*)((const char*)As + byte);
            }
#pragma unroll
            for (int fn = 0; fn < 4; ++fn) {
                const int row  = wc * 64 + fn * 16 + l16;
                const int byte = row * 128 + (((kh << 6) | (g << 4)) ^ ((row & 7) << 4));
                bfr[fn] = *(const short8*)((const char*)Bs + byte);
            }
#pragma unroll
            for (int fm = 0; fm < 4; ++fm)
#pragma unroll
                for (int fn = 0; fn < 4; ++fn)
                    acc[fm][fn] = __builtin_amdgcn_mfma_f32_16x16x32_bf16(a[fm], bfr[fn], acc[fm][fn], 0, 0, 0);
        }
    }

#pragma unroll
    for (int fm = 0; fm < 4; ++fm) {
        const int mb = m0 + wr * 64 + fm * 16 + g * 4;
#pragma unroll
        for (int fn = 0; fn < 4; ++fn) {
            const int n  = n0 + wc * 64 + fn * 16 + l16;
            const float bn = bias[n];
#pragma unroll
            for (int r = 0; r < 4; ++r)
                outp[(size_t)(mb + r) * D_MODEL + n] = acc[fm][fn][r] + bn;
        }
    }
}

// ---------------------------------------------------------------------------
// Flash attention v6: 32x32x16 MFMA, swapped QK^T, fully in-register P via
// cvt_pk_bf16 + permlane32_swap (no P LDS round trip).
// Grid (SEQ/128, BH) = 512 blocks, 4 waves; wave owns 32 q-rows.
// S^T C-layout: col=q=lane&31, row=key=(reg&3)+8*(reg>>2)+4*(lane>>5).
// PV A-frag: row=q=lane&31, k=key=(lane>>5)*8+j  -> built from C via
//   c[a][b] = cvt_pk(p[4a+2b], p[4a+2b+1]); swap(c[0][b],c[1][b]) and
//   swap(c[2][b],c[3][b]); frag = [s0.x, s1.x, s0.y, s1.y].
// O rows ≠ lane&31 -> alpha/l broadcast through per-wave LDS (rare/epilogue).
// ---------------------------------------------------------------------------
__global__ __launch_bounds__(256)
void flash_attn_mfma32(const ushort* __restrict__ Q, const ushort* __restrict__ K,
                       const ushort* __restrict__ Vt, ushort* __restrict__ AO)
{
    __shared__ ushort Kl[2][64 * 64];      // 64 keys x 64 d, swizzled rows
    __shared__ ushort Vl[2][64 * 64];      // 64 d x 64 keys, swizzled rows
    __shared__ float  Alds[4][32];         // per-wave q-indexed broadcast

    const int t    = threadIdx.x;
    const int w    = t >> 6;
    const int lane = t & 63;
    const int l32  = lane & 31;
    const int h    = lane >> 5;
    const int qt   = blockIdx.x;
    const int bh   = blockIdx.y;

    const int q0 = qt * 128 + w * 32;
    const size_t qkbase = (size_t)bh * SEQ * D_HEAD;
    const ushort* Vg0 = Vt + (size_t)bh * D_HEAD * SEQ;

    // Q fragments (B operand): lane holds Q[q=l32][d = ks*16 + h*8 .. +7]
    short8 qf[4];
    {
        const ushort* qp = Q + qkbase + (size_t)(q0 + l32) * D_HEAD + h * 8;
#pragma unroll
        for (int ks = 0; ks < 4; ++ks)
            qf[ks] = *(const short8*)(qp + ks * 16);
    }

    f32x16 o[2];
#pragma unroll
    for (int dt = 0; dt < 2; ++dt)
#pragma unroll
        for (int r = 0; r < 16; ++r) o[dt][r] = 0.f;
    float m_r = -INFINITY, l_r = 0.f;

    auto stage = [&](int ktile, int b) {
        const ushort* Kg = K + qkbase + (size_t)(ktile * 64) * D_HEAD;
        const ushort* Vg = Vg0 + ktile * 64;
#pragma unroll
        for (int it = 0; it < 2; ++it) {
            const int bb  = (it * 256 + t) * 16;
            const int row = bb >> 7;
            const int src = (bb & 127) ^ ((row & 7) << 4);
            const int lof = (it * 256 + (t & ~63)) * 8;
            gload_lds16(Kg + (size_t)row * D_HEAD + (src >> 1), &Kl[b][lof]);
            gload_lds16(Vg + (size_t)row * SEQ + (src >> 1), &Vl[b][lof]);
        }
    };

    stage(0, 0);
    __syncthreads();

    const int NT = SEQ / 64;
    for (int kt = 0; kt < NT; ++kt) {
        const int buf = kt & 1;
        if (kt + 1 < NT) stage(kt + 1, buf ^ 1);

        // ---- K fragments (A operand): row=key=nt*32+l32, byte-col=ks*32+h*16
        short8 kf[2][4];
#pragma unroll
        for (int nt = 0; nt < 2; ++nt) {
            const int row = nt * 32 + l32;
#pragma unroll
            for (int ks = 0; ks < 4; ++ks) {
                const int byte = row * 128 + ((ks * 32 + h * 16) ^ ((row & 7) << 4));
                kf[nt][ks] = *(const short8*)((const char*)&Kl[buf][0] + byte);
            }
        }
        // ---- V fragments (B operand): row=d=dt*32+l32, byte-col=ks*32+h*16
        short8 vf[2][4];
#pragma unroll
        for (int dt = 0; dt < 2; ++dt) {
            const int row = dt * 32 + l32;
#pragma unroll
            for (int ks = 0; ks < 4; ++ks) {
                const int byte = row * 128 + ((ks * 32 + h * 16) ^ ((row & 7) << 4));
                vf[dt][ks] = *(const short8*)((const char*)&Vl[buf][0] + byte);
            }
        }

        // ---- S^T = K @ Q^T (log2 domain; Q pre-scaled)
        f32x16 st[2];
#pragma unroll
        for (int nt = 0; nt < 2; ++nt)
#pragma unroll
            for (int r = 0; r < 16; ++r) st[nt][r] = 0.f;
        __builtin_amdgcn_s_setprio(1);
#pragma unroll
        for (int ks = 0; ks < 4; ++ks) {
            st[0] = __builtin_amdgcn_mfma_f32_32x32x16_bf16(kf[0][ks], qf[ks], st[0], 0, 0, 0);
            st[1] = __builtin_amdgcn_mfma_f32_32x32x16_bf16(kf[1][ks], qf[ks], st[1], 0, 0, 0);
        }
        __builtin_amdgcn_s_setprio(0);

        // ---- row softmax (row q = l32; values split lane/lane+32)
        float pmax = st[0][0];
#pragma unroll
        for (int r = 1; r < 16; ++r) pmax = fmaxf(pmax, st[0][r]);
#pragma unroll
        for (int r = 0; r < 16; ++r) pmax = fmaxf(pmax, st[1][r]);
        pmax = fmaxf(pmax, __shfl_xor(pmax, 32, 64));

        if (__any(pmax - m_r > 8.f)) {
            const float mnew  = fmaxf(m_r, pmax);
            const float alpha = exp2f(m_r - mnew);
            m_r = mnew;
            l_r *= alpha;
            Alds[w][l32] = alpha;              // both halves write same value
            float4 av[4];
#pragma unroll
            for (int a = 0; a < 4; ++a)
                av[a] = *(const float4*)&Alds[w][8 * a + 4 * h];
#pragma unroll
            for (int dt = 0; dt < 2; ++dt)
#pragma unroll
                for (int r = 0; r < 16; ++r)
                    o[dt][r] *= ((const float*)&av[r >> 2])[r & 3];
        }

        // ---- P = exp2(S - m), pack to bf16 fragments in-register
        float rs = 0.f;
        unsigned c[2][4][2];
#pragma unroll
        for (int nt = 0; nt < 2; ++nt) {
            float p[16];
#pragma unroll
            for (int r = 0; r < 16; ++r) {
                p[r] = exp2f(st[nt][r] - m_r);
                rs += p[r];
            }
#pragma unroll
            for (int a = 0; a < 4; ++a) {
                c[nt][a][0] = cvtpk_bf16(p[4 * a + 0], p[4 * a + 1]);
                c[nt][a][1] = cvtpk_bf16(p[4 * a + 2], p[4 * a + 3]);
            }
        }
        rs += __shfl_xor(rs, 32, 64);
        l_r += rs;

        short8 pa[4];
#pragma unroll
        for (int nt = 0; nt < 2; ++nt) {
#pragma unroll
            for (int half = 0; half < 2; ++half) {
                auto s0 = __builtin_amdgcn_permlane32_swap(c[nt][2 * half + 0][0],
                                                           c[nt][2 * half + 1][0], false, false);
                auto s1 = __builtin_amdgcn_permlane32_swap(c[nt][2 * half + 0][1],
                                                           c[nt][2 * half + 1][1], false, false);
                uint4v u;
                u[0] = s0[0]; u[1] = s1[0]; u[2] = s0[1]; u[3] = s1[1];
                pa[nt * 2 + half] = __builtin_bit_cast(short8, u);
            }
        }

        // ---- O += P @ V
        __builtin_amdgcn_s_setprio(1);
#pragma unroll
        for (int ks = 0; ks < 4; ++ks) {
            o[0] = __builtin_amdgcn_mfma_f32_32x32x16_bf16(pa[ks], vf[0][ks], o[0], 0, 0, 0);
            o[1] = __builtin_amdgcn_mfma_f32_32x32x16_bf16(pa[ks], vf[1][ks], o[1], 0, 0, 0);
        }
        __builtin_amdgcn_s_setprio(0);

        __syncthreads();   // staging drained (vmcnt0); all reads of buf done
    }

    // ---- epilogue: l broadcast per q, then AO[b][s][h*64+d] bf16
    Alds[w][l32] = l_r;
    float4 lv[4];
#pragma unroll
    for (int a = 0; a < 4; ++a)
        lv[a] = *(const float4*)&Alds[w][8 * a + 4 * h];

    const int b  = bh >> 4;
    const int hh = bh & 15;
#pragma unroll
    for (int r = 0; r < 16; ++r) {
        const int qrow = (r & 3) + 8 * (r >> 2) + 4 * h;
        const float inv = 1.f / ((const float*)&lv[r >> 2])[r & 3];
        const size_t row = (size_t)b * SEQ + q0 + qrow;
#pragma unroll
        for (int dt = 0; dt < 2; ++dt)
            AO[row * D_MODEL + hh * D_HEAD + dt * 32 + l32] = f2bf(o[dt][r] * inv);
    }
}

// ---------------------------------------------------------------------------
extern "C" void kernel_launch(void* const* d_in, const int* in_sizes, int n_in,
                              void* d_out, int out_size, void* d_ws, size_t ws_size,
                              hipStream_t stream)
{
    const float* x  = (const float*)d_in[0];
    const float* Wq = (const float*)d_in[1];
    const float* bq = (const float*)d_in[2];
    const float* Wk = (const float*)d_in[3];
    const float* bk = (const float*)d_in[4];
    const float* Wv = (const float*)d_in[5];
    const float* bv = (const float*)d_in[6];
    const float* Wo = (const float*)d_in[7];
    const float* bo = (const float*)d_in[8];
    float* out = (float*)d_out;

    const size_t WELT = (size_t)D_MODEL * D_MODEL;   // 1M
    ushort* xb  = (ushort*)d_ws;        // [0,1N): x bf16
    ushort* Wqt = xb + NELT;            // [1N,2N): Wq/Wk/Wv/Wo transposed
    ushort* Wot = Wqt + 3 * WELT;
    ushort* Qb  = xb + 2 * NELT;        // [2N,3N): Q head layout (pre-scaled)
    ushort* Kb  = Qb + NELT;            // [3N,4N)
    ushort* Vtb = Kb + NELT;            // [4N,5N): V transposed head layout
    ushort* AOb = xb + 5 * NELT;        // [5N,6N): attention out bf16

    f32_to_bf16_kernel<<<dim3(M_TOT * D_MODEL / 4 / 256), 256, 0, stream>>>(x, xb, M_TOT * D_MODEL / 4);
    transpose_w4_kernel<<<dim3(D_MODEL / 64, D_MODEL / 64, 4), 256, 0, stream>>>(Wq, Wk, Wv, Wo, Wqt);
    gemm_qkv_mfma<<<dim3(3 * D_MODEL / 128, M_TOT / 128), 256, 0, stream>>>(xb, Wqt, bq, bk, bv, Qb);
    flash_attn_mfma32<<<dim3(SEQ / 128, BATCH * N_HEADS), 256, 0, stream>>>(Qb, Kb, Vtb, AOb);
    gemm_out_mfma<<<dim3(D_MODEL / 128, M_TOT / 128), 256, 0, stream>>>(AOb, Wot, bo, out);
}